// Round 5
// baseline (42.561 us; speedup 1.0000x reference)
//
#include <hip/hip_runtime.h>
#include <math.h>

#define HH 384
#define WW 384
#define HWSZ (HH * WW)
#define NPIX (2 * HWSZ)
#define KSEL 11
#define TW 64             // tile width = one wave
#define TH 2              // 2 output rows per block (1 wave, 2 px/thread)
#define NTHR 64           // one wave per block
#define TPW (TW + 10)     // 74
#define TPH (TH + 10)     // 12
#define TILE_N (TPW * TPH)  // 888 float4 = 14208 B
#define NBX (WW / TW)     // 6
#define NBY (HH / TH)     // 192
#define NBLK (2 * NBX * NBY)  // 2304 = 9 * 256 -> exact CU balance

__device__ __forceinline__ float fast_sqrtf(float x) {
    float r;
    asm("v_sqrt_f32 %0, %1" : "=v"(r) : "v"(x));
    return r;
}

__device__ __forceinline__ float wave_sum(float v) {
#pragma unroll
    for (int off = 32; off > 0; off >>= 1) v += __shfl_down(v, off, 64);
    return v;
}

// Key: high 20 bits = d^2 (f32 bits truncated), low 12 = pre-quantized
// neighbor alpha (staged into tile.w). d2 >= 0 so float min/max order
// == lexicographic (d2, payload).
__device__ __forceinline__ float make_key(const float4 c, const float4 n) {
    const float e0 = c.x - n.x;
    const float e1 = c.y - n.y;
    const float e2 = c.z - n.z;
    float d2 = e0 * e0;
    d2 = __builtin_fmaf(e1, e1, d2);
    d2 = __builtin_fmaf(e2, e2, d2);
    const unsigned bits = (__float_as_uint(d2) & 0xFFFFF000u) | __float_as_uint(n.w);
    return __uint_as_float(bits);
}

// Merge an unsorted pair into sorted-ascending bd[0..10], keep smallest 11.
// Nested fminf/fmaxf lets clang fuse v_min3_f32 / v_max3_f32 and schedule
// freely (no inline asm in the hot loop).
__device__ __forceinline__ void merge2(float bd[KSEL], float a, float b) {
    const float p0 = fminf(a, b);
    const float p1 = fmaxf(a, b);
    float nb[KSEL];
    nb[0] = fminf(bd[0], p0);
    nb[1] = fminf(fminf(bd[1], fmaxf(bd[0], p0)), p1);
#pragma unroll
    for (int j = 2; j < KSEL; ++j)
        nb[j] = fminf(fminf(bd[j], fmaxf(bd[j - 1], p0)), fmaxf(bd[j - 2], p1));
#pragma unroll
    for (int j = 0; j < KSEL; ++j) bd[j] = nb[j];
}

__device__ __forceinline__ void merge1(float bd[KSEL], float p) {
    float cd = p;
#pragma unroll
    for (int j = 0; j < KSEL; ++j) {
        const float mx = fmaxf(cd, bd[j]);
        bd[j] = fminf(cd, bd[j]);
        cd = mx;
    }
}

// Unpack selected 11 keys; accumulate |dist - (ac - alpha_n)| with exact ac.
__device__ __forceinline__ float acc_ddc(const float bd[KSEL], float ac) {
    float s = 0.f;
#pragma unroll
    for (int j = 0; j < KSEL; ++j) {
        const unsigned kb = __float_as_uint(bd[j]);
        const float d2 = __uint_as_float((kb & 0xFFFFF000u) | 0x800u); // midpoint
        const float ad = __builtin_fmaf((float)(kb & 0xFFFu), -1.0f / 4095.0f, ac);
        s += fabsf(fast_sqrtf(d2) - ad);
    }
    return s;
}

__global__ __launch_bounds__(NTHR, 1) void matting_main(
    const float* __restrict__ alpha,
    const float* __restrict__ trimap,
    const float* __restrict__ image,
    float* __restrict__ ws)
{
    __shared__ float4 tile[TILE_N];   // denormalized rgb + quantized-alpha bits

    const int bx = blockIdx.x % NBX;
    const int by = (blockIdx.x / NBX) % NBY;
    const int b  = blockIdx.x / (NBX * NBY);

    const float* i0 = image + b * 3 * HWSZ;
    const float* i1 = i0 + HWSZ;
    const float* i2 = i1 + HWSZ;
    const float* ap = alpha + b * HWSZ;

    const int gy0 = by * TH - 5, gx0 = bx * TW - 5;
#pragma unroll
    for (int it = 0; it < (TILE_N + NTHR - 1) / NTHR; ++it) {
        const int t = it * NTHR + threadIdx.x;
        if (t < TILE_N) {
            const int ry = t / TPW, rx = t - ry * TPW;
            const int gy = gy0 + ry, gx = gx0 + rx;
            float4 v = make_float4(0.f, 0.f, 0.f, 0.f);
            if ((unsigned)gy < (unsigned)HH && (unsigned)gx < (unsigned)WW) {
                const int gi = gy * WW + gx;
                v.x = __builtin_fmaf(i0[gi], 0.229f, 0.485f);
                v.y = __builtin_fmaf(i1[gi], 0.224f, 0.456f);
                v.z = __builtin_fmaf(i2[gi], 0.225f, 0.406f);
                v.w = __uint_as_float((unsigned)(ap[gi] * 4095.0f)); // payload
            }
            tile[t] = v;
        }
    }
    __syncthreads();

    const int lane = threadIdx.x;
    const float4* tp = &tile[lane];
    const float4 c0 = tp[5 * TPW + 5];   // center, row y0
    const float4 c1 = tp[6 * TPW + 5];   // center, row y0+1

    float bd0[KSEL], bd1[KSEL];
#pragma unroll
    for (int j = 0; j < KSEL; ++j) {
        bd0[j] = __uint_as_float(0x7F800000u);
        bd1[j] = __uint_as_float(0x7F800000u);
    }

    // 12 shared window rows: row di feeds chain0 (rows 0..10) and chain1
    // (rows 1..11). One ds_read_b128 serves both chains; two independent
    // merge networks give the ILP that hides VALU + LDS latency.
#pragma unroll
    for (int di = 0; di < 12; ++di) {
        const float4* row = tp + di * TPW;
#pragma unroll
        for (int h = 0; h < 5; ++h) {
            const float4 na = row[2 * h];
            const float4 nb = row[2 * h + 1];
            if (di < 11) merge2(bd0, make_key(c0, na), make_key(c0, nb));
            if (di > 0)  merge2(bd1, make_key(c1, na), make_key(c1, nb));
        }
        const float4 nz = row[10];
        if (di < 11) merge1(bd0, make_key(c0, nz));
        if (di > 0)  merge1(bd1, make_key(c1, nz));
    }

    // own-pixel terms (exact alpha / trimap, L2-resident)
    const int rem0 = (by * TH) * WW + (bx * TW + lane);
    const int rem1 = rem0 + WW;
    const float a0 = ap[rem0], a1 = ap[rem1];
    const float t0 = trimap[b * HWSZ + rem0], t1 = trimap[b * HWSZ + rem1];

    const float k0 = (t0 != 0.5f) ? 1.f : 0.f;
    const float k1 = (t1 != 0.5f) ? 1.f : 0.f;
    const float s0 = 1.f - k0, s1 = 1.f - k1;

    const float known_v = k0 * fabsf(a0 - t0) + k1 * fabsf(a1 - t1);
    const float known_c = k0 + k1;
    const float dsum = s0 * acc_ddc(bd0, a0) + s1 * acc_ddc(bd1, a1);
    const float samp = s0 + s1;

    const float v0 = wave_sum(known_v);
    const float v1 = wave_sum(known_c);
    const float v2 = wave_sum(dsum);
    const float v3 = wave_sum(samp);
    if (lane == 0) {
        float* wsb = ws + blockIdx.x * 4;
        wsb[0] = v0; wsb[1] = v1; wsb[2] = v2; wsb[3] = v3;
    }
}

__global__ __launch_bounds__(256) void matting_finalize(
    const float* __restrict__ ws, float* __restrict__ out)
{
    float a = 0, b = 0, c = 0, d = 0;
    for (int i = threadIdx.x; i < NBLK; i += 256) {
        a += ws[i * 4 + 0];
        b += ws[i * 4 + 1];
        c += ws[i * 4 + 2];
        d += ws[i * 4 + 3];
    }
    a = wave_sum(a); b = wave_sum(b); c = wave_sum(c); d = wave_sum(d);
    __shared__ float sred[4][4];
    const int wid = threadIdx.x >> 6, lane = threadIdx.x & 63;
    if (lane == 0) { sred[wid][0] = a; sred[wid][1] = b; sred[wid][2] = c; sred[wid][3] = d; }
    __syncthreads();
    if (threadIdx.x == 0) {
        float ksum = 0, kcnt = 0, dsum = 0, scnt = 0;
#pragma unroll
        for (int w = 0; w < 4; ++w) {
            ksum += sred[w][0]; kcnt += sred[w][1]; dsum += sred[w][2]; scnt += sred[w][3];
        }
        const float known = (kcnt > 0.f) ? ksum * (1.0f / (float)NPIX) : 0.f;
        const float ddc   = (scnt > 0.f) ? dsum * (0.1f / ((float)NPIX * (float)KSEL)) : 0.f;
        out[0] = known + ddc;
        out[1] = known;
        out[2] = ddc;
    }
}

extern "C" void kernel_launch(void* const* d_in, const int* in_sizes, int n_in,
                              void* d_out, int out_size, void* d_ws, size_t ws_size,
                              hipStream_t stream) {
    const float* alpha  = (const float*)d_in[0];  // pred_alpha  [2,1,384,384]
    const float* trimap = (const float*)d_in[1];  // gt_trimap   [2,1,384,384]
    const float* image  = (const float*)d_in[2];  // input_image [2,3,384,384]
    float* out = (float*)d_out;
    float* ws  = (float*)d_ws;

    matting_main<<<NBLK, NTHR, 0, stream>>>(alpha, trimap, image, ws);
    matting_finalize<<<1, 256, 0, stream>>>(ws, out);
}

// Round 6
// 28.045 us; speedup vs baseline: 1.5176x; 1.5176x over previous
//
#include <hip/hip_runtime.h>
#include <math.h>

#define HH 384
#define WW 384
#define HWSZ (HH * WW)
#define NPIX (2 * HWSZ)
#define KSEL 11
#define TW 48                 // tile width
#define TH 12                 // tile height (4 waves x 3 rows)
#define TPW (TW + 10)         // 58
#define TPH (TH + 10)         // 22
#define TILE_N (TPW * TPH)    // 1276 float4
#define NBX (WW / TW)         // 8
#define NBY (HH / TH)         // 32
#define NBLK (2 * NBX * NBY)  // 512 = exactly 2 blocks/CU
#define NW 4                  // waves per block
#define RPW 3                 // rows per wave
#define PXW (TW * RPW)        // 144 px per wave
#define NGROUP (NBLK * NW)    // 2048 partial groups

__device__ __forceinline__ float fast_sqrtf(float x) {
    float r;
    asm("v_sqrt_f32 %0, %1" : "=v"(r) : "v"(x));
    return r;
}

__device__ __forceinline__ float wave_sum(float v) {
#pragma unroll
    for (int off = 32; off > 0; off >>= 1) v += __shfl_down(v, off, 64);
    return v;
}

// Key: high 20 bits = d^2 (f32 bits truncated), low 12 = pre-quantized
// neighbor alpha. d2 >= 0 so float min/max order == lexicographic.
__device__ __forceinline__ float make_key(const float4 c, const float4 n) {
    const float e0 = c.x - n.x;
    const float e1 = c.y - n.y;
    const float e2 = c.z - n.z;
    float d2 = e0 * e0;
    d2 = __builtin_fmaf(e1, e1, d2);
    d2 = __builtin_fmaf(e2, e2, d2);
    const unsigned bits = (__float_as_uint(d2) & 0xFFFFF000u) | __float_as_uint(n.w);
    return __uint_as_float(bits);
}

// Merge an unsorted pair into sorted-ascending bd[0..10], keep smallest 11.
__device__ __forceinline__ void merge2(float bd[KSEL], float a, float b) {
    const float p0 = fminf(a, b);
    const float p1 = fmaxf(a, b);
    float nb[KSEL];
    nb[0] = fminf(bd[0], p0);
    nb[1] = fminf(fminf(bd[1], fmaxf(bd[0], p0)), p1);
#pragma unroll
    for (int j = 2; j < KSEL; ++j)
        nb[j] = fminf(fminf(bd[j], fmaxf(bd[j - 1], p0)), fmaxf(bd[j - 2], p1));
#pragma unroll
    for (int j = 0; j < KSEL; ++j) bd[j] = nb[j];
}

__device__ __forceinline__ void merge1(float bd[KSEL], float p) {
    float cd = p;
#pragma unroll
    for (int j = 0; j < KSEL; ++j) {
        const float mx = fmaxf(cd, bd[j]);
        bd[j] = fminf(cd, bd[j]);
        cd = mx;
    }
}

__device__ __forceinline__ float acc_ddc(const float bd[KSEL], float ac) {
    float s = 0.f;
#pragma unroll
    for (int j = 0; j < KSEL; ++j) {
        const unsigned kb = __float_as_uint(bd[j]);
        const float d2 = __uint_as_float((kb & 0xFFFFF000u) | 0x800u); // midpoint
        const float ad = __builtin_fmaf((float)(kb & 0xFFFu), -1.0f / 4095.0f, ac);
        s += fabsf(fast_sqrtf(d2) - ad);
    }
    return s;
}

__global__ __launch_bounds__(256, 2) void matting_main(
    const float* __restrict__ alpha,
    const float* __restrict__ trimap,
    const float* __restrict__ image,
    float* __restrict__ ws)
{
    __shared__ float4 tile[TILE_N];          // denorm rgb + quantized-alpha bits
    __shared__ float aex[TH * TW];           // exact alpha, block-interior px
    __shared__ unsigned short list[NW][PXW]; // compacted unknown px per wave

    const int bx  = blockIdx.x % NBX;
    const int byy = (blockIdx.x / NBX) % NBY;
    const int b   = blockIdx.x / (NBX * NBY);

    const float* i0 = image + b * 3 * HWSZ;
    const float* i1 = i0 + HWSZ;
    const float* i2 = i1 + HWSZ;
    const float* ap = alpha + b * HWSZ;
    const float* tm = trimap + b * HWSZ;

    const int row0 = byy * TH, col0 = bx * TW;
    const int gy0 = row0 - 5, gx0 = col0 - 5;

    // ---- stage padded denormalized tile (zero pad == reference's unfold pad)
#pragma unroll
    for (int it = 0; it < (TILE_N + 255) / 256; ++it) {
        const int t = it * 256 + (int)threadIdx.x;
        if (t < TILE_N) {
            const int ry = t / TPW, rx = t - ry * TPW;
            const int gy = gy0 + ry, gx = gx0 + rx;
            float4 v = make_float4(0.f, 0.f, 0.f, 0.f);
            if ((unsigned)gy < (unsigned)HH && (unsigned)gx < (unsigned)WW) {
                const int gi = gy * WW + gx;
                v.x = __builtin_fmaf(i0[gi], 0.229f, 0.485f);
                v.y = __builtin_fmaf(i1[gi], 0.224f, 0.456f);
                v.z = __builtin_fmaf(i2[gi], 0.225f, 0.406f);
                v.w = __uint_as_float((unsigned)(ap[gi] * 4095.0f)); // payload
            }
            tile[t] = v;
        }
    }

    // ---- per-wave compaction of unknown px + known-L1 partials ----
    const int lane = threadIdx.x & 63;
    const int w    = threadIdx.x >> 6;
    unsigned cnt = 0;
    float kv = 0.f;
#pragma unroll
    for (int ch = 0; ch < 3; ++ch) {
        const int p = ch * 64 + lane;            // 0..191, valid < 144
        const bool in = p < PXW;
        const int rl = p / TW, cc = p - rl * TW; // row-in-wave 0..2, col 0..47
        const int rb = w * RPW + rl;             // block-local row 0..11
        float a = 0.f, tri = 1.f;
        if (in) {
            const int gi = (row0 + rb) * WW + col0 + cc;
            a = ap[gi];
            tri = tm[gi];
            aex[rb * TW + cc] = a;               // exact center alpha
        }
        const bool unk = in && (tri == 0.5f);
        kv += (in && tri != 0.5f) ? fabsf(a - tri) : 0.f;
        const unsigned long long m = __ballot(unk);
        if (unk)
            list[w][cnt + (unsigned)__popcll(m & ((1ull << lane) - 1ull))] =
                (unsigned short)((rb << 6) | cc);
        cnt += (unsigned)__popcll(m);
    }
    cnt = (unsigned)__builtin_amdgcn_readfirstlane((int)cnt);

    __syncthreads();

    // ---- selection rounds over compacted unknown pixels only ----
    float wdsum = 0.f;
    unsigned start = 0;
    while (start < cnt) {
        const unsigned i = start + (unsigned)lane;
        const bool act = i < cnt;
        const unsigned e = act ? (unsigned)list[w][i] : 0u;
        const int r = (int)(e >> 6), cc = (int)(e & 63u);

        const float4* tp = &tile[r * TPW + cc];  // window (di,dj) at tp[di*TPW+dj]
        const float4 c4 = tp[5 * TPW + 5];
        const float ac = aex[r * TW + cc];

        float bd[KSEL];
#pragma unroll
        for (int j = 0; j < KSEL; ++j) bd[j] = __uint_as_float(0x7F800000u);

#pragma unroll
        for (int di = 0; di < 11; ++di) {
            const float4* row = tp + di * TPW;
#pragma unroll
            for (int h = 0; h < 5; ++h)
                merge2(bd, make_key(c4, row[2 * h]), make_key(c4, row[2 * h + 1]));
            merge1(bd, make_key(c4, row[10]));
        }
        const float s = acc_ddc(bd, ac);
        wdsum += act ? s : 0.f;
        start += 64;
    }

    // ---- per-wave reduction, direct to ws (no cross-wave reduce needed) ----
    const float vkv = wave_sum(kv);
    const float vds = wave_sum(wdsum);
    if (lane == 0) {
        float* g = ws + (blockIdx.x * NW + w) * 4;
        g[0] = vkv;
        g[1] = (float)(PXW - (int)cnt);   // known count
        g[2] = vds;
        g[3] = (float)cnt;                // sample (unknown) count
    }
}

__global__ __launch_bounds__(256) void matting_finalize(
    const float* __restrict__ ws, float* __restrict__ out)
{
    float a = 0, b = 0, c = 0, d = 0;
    for (int i = threadIdx.x; i < NGROUP; i += 256) {
        a += ws[i * 4 + 0];
        b += ws[i * 4 + 1];
        c += ws[i * 4 + 2];
        d += ws[i * 4 + 3];
    }
    a = wave_sum(a); b = wave_sum(b); c = wave_sum(c); d = wave_sum(d);
    __shared__ float sred[4][4];
    const int wid = threadIdx.x >> 6, lane = threadIdx.x & 63;
    if (lane == 0) { sred[wid][0] = a; sred[wid][1] = b; sred[wid][2] = c; sred[wid][3] = d; }
    __syncthreads();
    if (threadIdx.x == 0) {
        float ksum = 0, kcnt = 0, dsum = 0, scnt = 0;
#pragma unroll
        for (int q = 0; q < 4; ++q) {
            ksum += sred[q][0]; kcnt += sred[q][1]; dsum += sred[q][2]; scnt += sred[q][3];
        }
        const float known = (kcnt > 0.f) ? ksum * (1.0f / (float)NPIX) : 0.f;
        const float ddc   = (scnt > 0.f) ? dsum * (0.1f / ((float)NPIX * (float)KSEL)) : 0.f;
        out[0] = known + ddc;
        out[1] = known;
        out[2] = ddc;
    }
}

extern "C" void kernel_launch(void* const* d_in, const int* in_sizes, int n_in,
                              void* d_out, int out_size, void* d_ws, size_t ws_size,
                              hipStream_t stream) {
    const float* alpha  = (const float*)d_in[0];  // pred_alpha  [2,1,384,384]
    const float* trimap = (const float*)d_in[1];  // gt_trimap   [2,1,384,384]
    const float* image  = (const float*)d_in[2];  // input_image [2,3,384,384]
    float* out = (float*)d_out;
    float* ws  = (float*)d_ws;                    // NGROUP*4 floats

    matting_main<<<NBLK, 256, 0, stream>>>(alpha, trimap, image, ws);
    matting_finalize<<<1, 256, 0, stream>>>(ws, out);
}